// Round 1
// baseline (578.189 us; speedup 1.0000x reference)
//
#include <hip/hip_runtime.h>

// Problem constants: N_A=N_B=30000, V=2, D=128
#define D 128
#define NODE_ROW 256       // V*D elements per node
#define AP 8               // (n,v) pairs per block in k_attn2
#define AR (AP * 2)        // x-rows per block in k_attn2 (P=2)

typedef __attribute__((ext_vector_type(8))) short short8;
typedef __attribute__((ext_vector_type(4))) float floatx4;

__device__ __forceinline__ ushort f2bf(float f) {
    unsigned int u = __float_as_uint(f);
    u += 0x7fffu + ((u >> 16) & 1u);
    return (ushort)(u >> 16);
}
__device__ __forceinline__ unsigned int pk2(float a, float b) {
    return (unsigned int)f2bf(a) | ((unsigned int)f2bf(b) << 16);
}
__device__ __forceinline__ void up8(uint4 u, float* f) {
    f[0] = __uint_as_float(u.x << 16); f[1] = __uint_as_float(u.x & 0xffff0000u);
    f[2] = __uint_as_float(u.y << 16); f[3] = __uint_as_float(u.y & 0xffff0000u);
    f[4] = __uint_as_float(u.z << 16); f[5] = __uint_as_float(u.z & 0xffff0000u);
    f[6] = __uint_as_float(u.w << 16); f[7] = __uint_as_float(u.w & 0xffff0000u);
}
__device__ __forceinline__ float bf2f(ushort h) {
    return __uint_as_float(((unsigned int)h) << 16);
}
__device__ __forceinline__ short8 ldfrag(const ushort* p) {
    union { uint4 u; short8 s; } cv;
    cv.u = *(const uint4*)p;
    return cv.s;
}
__device__ __forceinline__ void acc4(float4& a, float w, uint2 u) {
    a.x += w * __uint_as_float(u.x << 16);
    a.y += w * __uint_as_float(u.x & 0xffff0000u);
    a.z += w * __uint_as_float(u.y << 16);
    a.w += w * __uint_as_float(u.y & 0xffff0000u);
}

// ---------------- fp32 -> bf16 feature convert (both matrices, one launch) ----------------
__global__ __launch_bounds__(256) void k_f2b2(
    const float* __restrict__ srcA, const float* __restrict__ srcB,
    ushort* __restrict__ dstA, ushort* __restrict__ dstB, int n8) {
    int i = blockIdx.x * 256 + threadIdx.x;
    const float* s; ushort* d; int k;
    if (i < n8) { s = srcA; d = dstA; k = i; }
    else if (i < 2 * n8) { s = srcB; d = dstB; k = i - n8; }
    else return;
    const float4* sp = (const float4*)s + (size_t)k * 2;
    float4 a = sp[0], b = sp[1];
    uint4 o;
    o.x = pk2(a.x, a.y); o.y = pk2(a.z, a.w);
    o.z = pk2(b.x, b.y); o.w = pk2(b.z, b.w);
    ((uint4*)d)[k] = o;
}

// ---------------- CSR build ----------------

__global__ __launch_bounds__(256) void k_hist(
    const int* __restrict__ dst_ab, const int* __restrict__ dst_ba,
    int* __restrict__ cnt_ab, int* __restrict__ cnt_ba, int E) {
    int i = blockIdx.x * 256 + threadIdx.x;
    if (i >= E) return;
    atomicAdd(&cnt_ab[dst_ab[i]], 1);
    atomicAdd(&cnt_ba[dst_ba[i]], 1);
}

// Both scans in one launch (block 0: ab graph, block 1: ba graph).
// Writes exclusive prefix into start[] AND back into cnt[] (scatter cursor).
__global__ __launch_bounds__(1024) void k_scan2(
    int* __restrict__ cntB, int* __restrict__ startB, int nB_,
    int* __restrict__ cntA, int* __restrict__ startA, int nA_) {
    __shared__ int part[1024];
    int* cnt; int* start; int n;
    if (blockIdx.x == 0) { cnt = cntB; start = startB; n = nB_; }
    else                 { cnt = cntA; start = startA; n = nA_; }
    int t = threadIdx.x;
    int chunk = (n + 1023) >> 10;
    int lo = min(t * chunk, n), hi = min(lo + chunk, n);
    int s = 0;
    for (int i = lo; i < hi; i++) s += cnt[i];
    part[t] = s;
    __syncthreads();
    for (int d = 1; d < 1024; d <<= 1) {
        int v = (t >= d) ? part[t - d] : 0;
        __syncthreads();
        part[t] += v;
        __syncthreads();
    }
    int off = part[t] - s;
    for (int i = lo; i < hi; i++) {
        int c = cnt[i];
        start[i] = off;
        cnt[i] = off;          // running cursor for k_scatter
        off += c;
    }
    if (t == 1023) start[n] = off;
}

// scatter with absolute cursors (cnt holds start offsets after k_scan2)
__global__ __launch_bounds__(256) void k_scatter(
    const int* __restrict__ src_ab, const int* __restrict__ dst_ab,
    const float* __restrict__ val_ab,
    const int* __restrict__ src_ba, const int* __restrict__ dst_ba,
    const float* __restrict__ val_ba,
    int* __restrict__ cur_ab, int* __restrict__ cur_ba,
    int2* __restrict__ ep_ab, int2* __restrict__ ep_ba, int E) {
    int i = blockIdx.x * 256 + threadIdx.x;
    if (i >= E) return;
    {
        int pos = atomicAdd(&cur_ab[dst_ab[i]], 1);
        ep_ab[pos] = make_int2(src_ab[i], __float_as_int(val_ab[i]));
    }
    {
        int pos = atomicAdd(&cur_ba[dst_ba[i]], 1);
        ep_ba[pos] = make_int2(src_ba[i], __float_as_int(val_ba[i]));
    }
}

// ---------------- bf16 gather SpMM (4x unrolled for MLP) ----------------

__global__ __launch_bounds__(256) void k_gather_norm_bf(
    const ushort* __restrict__ feat, const int2* __restrict__ ep,
    const int* __restrict__ start, ushort* __restrict__ out, int n) {
    int node = blockIdx.x * 4 + (threadIdx.x >> 6);
    if (node >= n) return;
    int lane = threadIdx.x & 63;
    int lo = start[node], hi = start[node + 1];
    float4 acc = make_float4(0.f, 0.f, 0.f, 0.f);
    int i = lo;
    for (; i + 3 < hi; i += 4) {
        int2 p0 = ep[i], p1 = ep[i + 1], p2 = ep[i + 2], p3 = ep[i + 3];
        uint2 u0 = ((const uint2*)(feat + (size_t)p0.x * NODE_ROW))[lane];
        uint2 u1 = ((const uint2*)(feat + (size_t)p1.x * NODE_ROW))[lane];
        uint2 u2 = ((const uint2*)(feat + (size_t)p2.x * NODE_ROW))[lane];
        uint2 u3 = ((const uint2*)(feat + (size_t)p3.x * NODE_ROW))[lane];
        acc4(acc, __int_as_float(p0.y), u0);
        acc4(acc, __int_as_float(p1.y), u1);
        acc4(acc, __int_as_float(p2.y), u2);
        acc4(acc, __int_as_float(p3.y), u3);
    }
    for (; i < hi; i++) {
        int2 p = ep[i];
        uint2 u = ((const uint2*)(feat + (size_t)p.x * NODE_ROW))[lane];
        acc4(acc, __int_as_float(p.y), u);
    }
    float ss = acc.x * acc.x + acc.y * acc.y + acc.z * acc.z + acc.w * acc.w;
    #pragma unroll
    for (int o = 16; o > 0; o >>= 1) ss += __shfl_xor(ss, o, 32);
    float sc = 1.0f / fmaxf(sqrtf(ss), 1e-12f);
    uint2 o;
    o.x = pk2(acc.x * sc, acc.y * sc);
    o.y = pk2(acc.z * sc, acc.w * sc);
    ((uint2*)(out + (size_t)node * NODE_ROW))[lane] = o;
}

__global__ __launch_bounds__(256) void k_gather2_bf(
    const ushort* __restrict__ featP, const ushort* __restrict__ featQ,
    const int2* __restrict__ ep, const int* __restrict__ start,
    ushort* __restrict__ outP, ushort* __restrict__ outQ, int n) {
    int node = blockIdx.x * 4 + (threadIdx.x >> 6);
    if (node >= n) return;
    int lane = threadIdx.x & 63;
    int lo = start[node], hi = start[node + 1];
    float4 aP = make_float4(0.f, 0.f, 0.f, 0.f);
    float4 aQ = make_float4(0.f, 0.f, 0.f, 0.f);
    int i = lo;
    for (; i + 3 < hi; i += 4) {
        int2 p0 = ep[i], p1 = ep[i + 1], p2 = ep[i + 2], p3 = ep[i + 3];
        size_t o0 = (size_t)p0.x * NODE_ROW, o1 = (size_t)p1.x * NODE_ROW;
        size_t o2 = (size_t)p2.x * NODE_ROW, o3 = (size_t)p3.x * NODE_ROW;
        uint2 uP0 = ((const uint2*)(featP + o0))[lane];
        uint2 uQ0 = ((const uint2*)(featQ + o0))[lane];
        uint2 uP1 = ((const uint2*)(featP + o1))[lane];
        uint2 uQ1 = ((const uint2*)(featQ + o1))[lane];
        uint2 uP2 = ((const uint2*)(featP + o2))[lane];
        uint2 uQ2 = ((const uint2*)(featQ + o2))[lane];
        uint2 uP3 = ((const uint2*)(featP + o3))[lane];
        uint2 uQ3 = ((const uint2*)(featQ + o3))[lane];
        float w0 = __int_as_float(p0.y), w1 = __int_as_float(p1.y);
        float w2 = __int_as_float(p2.y), w3 = __int_as_float(p3.y);
        acc4(aP, w0, uP0); acc4(aQ, w0, uQ0);
        acc4(aP, w1, uP1); acc4(aQ, w1, uQ1);
        acc4(aP, w2, uP2); acc4(aQ, w2, uQ2);
        acc4(aP, w3, uP3); acc4(aQ, w3, uQ3);
    }
    for (; i < hi; i++) {
        int2 p = ep[i];
        float w = __int_as_float(p.y);
        size_t off = (size_t)p.x * NODE_ROW;
        uint2 uP = ((const uint2*)(featP + off))[lane];
        uint2 uQ = ((const uint2*)(featQ + off))[lane];
        acc4(aP, w, uP); acc4(aQ, w, uQ);
    }
    uint2 oP, oQ;
    oP.x = pk2(aP.x, aP.y); oP.y = pk2(aP.z, aP.w);
    oQ.x = pk2(aQ.x, aQ.y); oQ.y = pk2(aQ.z, aQ.w);
    ((uint2*)(outP + (size_t)node * NODE_ROW))[lane] = oP;
    ((uint2*)(outQ + (size_t)node * NODE_ROW))[lane] = oQ;
}

// ---------------- weight fp32 -> bf16 pre-convert ----------------
__global__ __launch_bounds__(256) void k_cvt(
    const float* __restrict__ W1, const float* __restrict__ W2,
    const float* __restrict__ Win, const float* __restrict__ Wout,
    ushort* __restrict__ dst) {
    int idx = (blockIdx.x * 256 + threadIdx.x) * 4;
    if (idx >= 98304) return;
    const float* s; int off;
    if (idx < 16384)      { s = W1;  off = idx; }
    else if (idx < 32768) { s = W2;  off = idx - 16384; }
    else if (idx < 81920) { s = Win; off = idx - 32768; }
    else                  { s = Wout; off = idx - 81920; }
    float4 f = *(const float4*)(s + off);
    uint2 p;
    p.x = pk2(f.x, f.y);
    p.y = pk2(f.z, f.w);
    *(uint2*)(dst + idx) = p;
}

// ---------------- k_projm2: both projections in one launch (gridDim.y selects set) ----------------
__global__ __launch_bounds__(128) void k_projm2(
    const ushort* __restrict__ in1, const ushort* __restrict__ Wb1,
    const float* __restrict__ b1, const float* __restrict__ g1,
    const float* __restrict__ be1,
    const ushort* __restrict__ in2, const ushort* __restrict__ Wb2,
    const float* __restrict__ b2, const float* __restrict__ g2,
    const float* __restrict__ be2,
    ushort* __restrict__ xbuf) {
    __shared__ ushort xn[16][136];
    __shared__ float yb[16][128];
    int p = blockIdx.y;                       // wave-uniform select
    const ushort* in = p ? in2 : in1;
    const ushort* Wb = p ? Wb2 : Wb1;
    const float*  b  = p ? b2  : b1;
    const float*  g  = p ? g2  : g1;
    const float*  be = p ? be2 : be1;
    int t = threadIdx.x;
    size_t rowbase = (size_t)blockIdx.x * 16;
    int r = t >> 3, i = t & 7;

    {
        const ushort* gp = in + (rowbase + r) * D + i * 16;
        float v[16];
        up8(((const uint4*)gp)[0], v);
        up8(((const uint4*)gp)[1], v + 8);
        float ss = 0.f;
        #pragma unroll
        for (int e = 0; e < 16; e++) ss += v[e] * v[e];
        ss += __shfl_xor(ss, 1, 8);
        ss += __shfl_xor(ss, 2, 8);
        ss += __shfl_xor(ss, 4, 8);
        float sc = 1.0f / fmaxf(sqrtf(ss), 1e-12f);
        uint4 w0, w1;
        w0.x = pk2(v[0]*sc, v[1]*sc);   w0.y = pk2(v[2]*sc, v[3]*sc);
        w0.z = pk2(v[4]*sc, v[5]*sc);   w0.w = pk2(v[6]*sc, v[7]*sc);
        w1.x = pk2(v[8]*sc, v[9]*sc);   w1.y = pk2(v[10]*sc, v[11]*sc);
        w1.z = pk2(v[12]*sc, v[13]*sc); w1.w = pk2(v[14]*sc, v[15]*sc);
        ushort* dst = &xn[r][i * 16];
        ((uint4*)dst)[0] = w0;
        ((uint4*)dst)[1] = w1;
    }
    __syncthreads();

    {
        int lane = t & 63, w = t >> 6, c = lane & 15, quad = lane >> 4;
        short8 af[4];
        #pragma unroll
        for (int kt = 0; kt < 4; kt++)
            af[kt] = ldfrag(&xn[c][kt * 32 + quad * 8]);
        #pragma unroll
        for (int nt2 = 0; nt2 < 4; nt2++) {
            int j = (w * 4 + nt2) * 16 + c;
            floatx4 acc = {0.f, 0.f, 0.f, 0.f};
            #pragma unroll
            for (int kt = 0; kt < 4; kt++) {
                short8 bfr = ldfrag(Wb + (size_t)j * 128 + kt * 32 + quad * 8);
                acc = __builtin_amdgcn_mfma_f32_16x16x32_bf16(af[kt], bfr, acc, 0, 0, 0);
            }
            float bj = b[j];
            #pragma unroll
            for (int rg = 0; rg < 4; rg++)
                yb[quad * 4 + rg][j] = acc[rg] + bj;
        }
    }
    __syncthreads();

    {
        float v[16];
        const float* yr = &yb[r][i * 16];
        #pragma unroll
        for (int e = 0; e < 16; e++) v[e] = yr[e];
        float s1 = 0.f, s2 = 0.f;
        #pragma unroll
        for (int e = 0; e < 16; e++) { s1 += v[e]; s2 += v[e] * v[e]; }
        s1 += __shfl_xor(s1, 1, 8); s2 += __shfl_xor(s2, 1, 8);
        s1 += __shfl_xor(s1, 2, 8); s2 += __shfl_xor(s2, 2, 8);
        s1 += __shfl_xor(s1, 4, 8); s2 += __shfl_xor(s2, 4, 8);
        float mu = s1 * (1.0f / 128.0f);
        float var = s2 * (1.0f / 128.0f) - mu * mu;
        float rs = rsqrtf(var + 1e-5f);
        const float* gg = g + i * 16;
        const float* bb = be + i * 16;
        float res[16];
        #pragma unroll
        for (int e = 0; e < 16; e++)
            res[e] = fmaxf((v[e] - mu) * rs * gg[e] + bb[e], 0.f);
        ushort* op = xbuf + ((rowbase + r) * 2 + p) * D + i * 16;
        uint4 w0, w1;
        w0.x = pk2(res[0], res[1]);   w0.y = pk2(res[2], res[3]);
        w0.z = pk2(res[4], res[5]);   w0.w = pk2(res[6], res[7]);
        w1.x = pk2(res[8], res[9]);   w1.y = pk2(res[10], res[11]);
        w1.z = pk2(res[12], res[13]); w1.w = pk2(res[14], res[15]);
        ((uint4*)op)[0] = w0;
        ((uint4*)op)[1] = w1;
    }
}

// ---------------- k_attn2: slim LDS + fused scores/softmax/a@v phase ----------------
__global__ __launch_bounds__(384, 8) void k_attn2(
    const ushort* __restrict__ xbuf,
    const ushort* __restrict__ Winb, const float* __restrict__ binq,
    const ushort* __restrict__ Woutb, const float* __restrict__ bout,
    const float* __restrict__ lng, const float* __restrict__ lnb,
    float* __restrict__ out) {
    __shared__ ushort xb[AR][136];     // x rows bf16 (A-operand + residual)
    __shared__ float qk[AR][256];      // q(scaled),k fp32; y reuses 0..127
    __shared__ ushort vb[AR][136];     // v bf16
    __shared__ ushort ob[AR][136];     // attn-out bf16 (A-operand)
    __shared__ float mu_s[AR], rs_s[AR];
    int t = threadIdx.x;
    int lane = t & 63, w = t >> 6;
    int c = lane & 15, quad = lane >> 4;
    size_t pairbase = (size_t)blockIdx.x * AP;
    size_t rowbase = pairbase * 2;

    // load bf16 x into xb
    const uint2* gx = (const uint2*)(xbuf + rowbase * D);
    for (int i = t; i < AR * D / 4; i += 384) {
        int r = i >> 5;
        int col = (i & 31) * 4;
        *(uint2*)&xb[r][col] = gx[i];
    }
    __syncthreads();

    // QKV GEMM via MFMA: M=16, N=384 (wave w -> ntiles w*4..w*4+3)
    {
        short8 af[4];
        #pragma unroll
        for (int kt = 0; kt < 4; kt++)
            af[kt] = ldfrag(&xb[c][kt * 32 + quad * 8]);
        #pragma unroll
        for (int nt2 = 0; nt2 < 4; nt2++) {
            int j = (w * 4 + nt2) * 16 + c;
            floatx4 acc = {0.f, 0.f, 0.f, 0.f};
            #pragma unroll
            for (int kt = 0; kt < 4; kt++) {
                short8 bfr = ldfrag(Winb + (size_t)j * 128 + kt * 32 + quad * 8);
                acc = __builtin_amdgcn_mfma_f32_16x16x32_bf16(af[kt], bfr, acc, 0, 0, 0);
            }
            float bj = binq[j];
            if (j < 256) {
                float sc = (j < 128) ? 0.17677669529663687f : 1.0f;
                #pragma unroll
                for (int rg = 0; rg < 4; rg++)
                    qk[quad * 4 + rg][j] = (acc[rg] + bj) * sc;
            } else {
                #pragma unroll
                for (int rg = 0; rg < 4; rg++)
                    vb[quad * 4 + rg][j - 256] = f2bf(acc[rg] + bj);
            }
        }
    }
    __syncthreads();

    // FUSED scores + softmax + a@v: 256 threads, attention weights in registers.
    // t = [pp:3][h:2][pq:1][kk:1][half:1]; each thread: 16-elem partial dot,
    // shfl(1) completes dot, shfl(2) exchanges the two scores, then writes its
    // 8 output columns of ob.
    if (t < 256) {
        int half = t & 1, kk = (t >> 1) & 1, pq = (t >> 2) & 1;
        int h = (t >> 3) & 3, pp = t >> 5;
        int qrow = 2 * pp + pq;
        const float4* qp = (const float4*)&qk[qrow][h * 32 + half * 16];
        const float4* kp = (const float4*)&qk[2 * pp + kk][128 + h * 32 + half * 16];
        float s = 0.f;
        #pragma unroll
        for (int m = 0; m < 4; m++) {
            float4 qv = qp[m], kv = kp[m];
            s += qv.x * kv.x + qv.y * kv.y + qv.z * kv.z + qv.w * kv.w;
        }
        s += __shfl_xor(s, 1, 64);          // complete 32-elem dot
        float so = __shfl_xor(s, 2, 64);    // partner score (other kk)
        float s0 = kk ? so : s;
        float s1 = kk ? s : so;
        float m0 = fmaxf(s0, s1);
        float e0 = __expf(s0 - m0), e1 = __expf(s1 - m0);
        float inv = 1.f / (e0 + e1);
        float a0 = e0 * inv, a1 = e1 * inv;
        int cbase = h * 32 + kk * 16 + half * 8;
        const uint2* v0p = (const uint2*)&vb[2 * pp][cbase];
        const uint2* v1p = (const uint2*)&vb[2 * pp + 1][cbase];
        ushort* op = &ob[qrow][cbase];
        #pragma unroll
        for (int m = 0; m < 2; m++) {
            uint2 u0 = v0p[m], u1 = v1p[m];
            float o0 = a0 * __uint_as_float(u0.x << 16)         + a1 * __uint_as_float(u1.x << 16);
            float o1 = a0 * __uint_as_float(u0.x & 0xffff0000u) + a1 * __uint_as_float(u1.x & 0xffff0000u);
            float o2 = a0 * __uint_as_float(u0.y << 16)         + a1 * __uint_as_float(u1.y << 16);
            float o3 = a0 * __uint_as_float(u0.y & 0xffff0000u) + a1 * __uint_as_float(u1.y & 0xffff0000u);
            uint2 pw;
            pw.x = pk2(o0, o1); pw.y = pk2(o2, o3);
            ((uint2*)op)[m] = pw;
        }
    }
    __syncthreads();

    // out-proj via MFMA + bias + residual -> y in qk cols 0..127 (q,k dead)
    if (w < 4) {
        short8 af[4];
        #pragma unroll
        for (int kt = 0; kt < 4; kt++)
            af[kt] = ldfrag(&ob[c][kt * 32 + quad * 8]);
        #pragma unroll
        for (int nt2 = 0; nt2 < 2; nt2++) {
            int j = (w * 2 + nt2) * 16 + c;
            floatx4 acc = {0.f, 0.f, 0.f, 0.f};
            #pragma unroll
            for (int kt = 0; kt < 4; kt++) {
                short8 bfr = ldfrag(Woutb + (size_t)j * 128 + kt * 32 + quad * 8);
                acc = __builtin_amdgcn_mfma_f32_16x16x32_bf16(af[kt], bfr, acc, 0, 0, 0);
            }
            float bj = bout[j];
            #pragma unroll
            for (int rg = 0; rg < 4; rg++) {
                int row = quad * 4 + rg;
                qk[row][j] = acc[rg] + bj + bf2f(xb[row][j]);
            }
        }
    }
    __syncthreads();

    // LN stats per row on y (qk cols 0..127)
    if (t < 128) {
        int r = t >> 3, i = t & 7;
        float s1 = 0.f, s2 = 0.f;
        const float* yr = &qk[r][i * 16];
        #pragma unroll
        for (int cc = 0; cc < 16; cc++) { float v = yr[cc]; s1 += v; s2 += v * v; }
        s1 += __shfl_down(s1, 4, 8); s2 += __shfl_down(s2, 4, 8);
        s1 += __shfl_down(s1, 2, 8); s2 += __shfl_down(s2, 2, 8);
        s1 += __shfl_down(s1, 1, 8); s2 += __shfl_down(s2, 1, 8);
        if (i == 0) {
            float mu = s1 / D;
            float var = s2 / D - mu * mu;
            mu_s[r] = mu; rs_s[r] = rsqrtf(var + 1e-5f);
        }
    }
    __syncthreads();

    // LN apply + mean over P
    if (t < 128) {
        int j = t;
        float gj = lng[j], bj = lnb[j];
        #pragma unroll
        for (int pp = 0; pp < AP; pp++) {
            int r0 = pp * 2, r1 = r0 + 1;
            float v0 = (qk[r0][j] - mu_s[r0]) * rs_s[r0] * gj + bj;
            float v1 = (qk[r1][j] - mu_s[r1]) * rs_s[r1] * gj + bj;
            out[(pairbase + pp) * D + j] = 0.5f * (v0 + v1);
        }
    }
}

extern "C" void kernel_launch(void* const* d_in, const int* in_sizes, int n_in,
                              void* d_out, int out_size, void* d_ws, size_t ws_size,
                              hipStream_t stream) {
    const float* feat_A = (const float*)d_in[0];
    const float* feat_B = (const float*)d_in[1];
    const int*   src_ab = (const int*)d_in[2];
    const int*   dst_ab = (const int*)d_in[3];
    const float* val_ab = (const float*)d_in[4];
    const int*   src_ba = (const int*)d_in[5];
    const int*   dst_ba = (const int*)d_in[6];
    const float* val_ba = (const float*)d_in[7];
    const float* W1 = (const float*)d_in[8];
    const float* b1 = (const float*)d_in[9];
    const float* g1 = (const float*)d_in[10];
    const float* be1 = (const float*)d_in[11];
    const float* W2 = (const float*)d_in[12];
    const float* b2 = (const float*)d_in[13];
    const float* g2 = (const float*)d_in[14];
    const float* be2 = (const float*)d_in[15];
    const float* Win = (const float*)d_in[16];
    const float* binq = (const float*)d_in[17];
    const float* Wout = (const float*)d_in[18];
    const float* bout = (const float*)d_in[19];
    const float* lng = (const float*)d_in[20];
    const float* lnb = (const float*)d_in[21];

    int E  = in_sizes[2];
    int nA = in_sizes[0] / NODE_ROW;   // 30000
    int nB = in_sizes[1] / NODE_ROW;   // 30000
    int rowsA = nA * 2;                // N_A * V = 60000
    size_t nodeElems = (size_t)nA * NODE_ROW;

    // Workspace layout (identical to passing R6)
    ushort* fbA  = (ushort*)d_ws;
    ushort* fbB  = fbA + nodeElems;
    ushort* hB   = fbB + nodeElems;
    ushort* hA1  = hB + nodeElems;
    ushort* hA2  = hA1 + nodeElems;
    ushort* xbuf = hA2 + nodeElems;
    ushort* Wbf  = xbuf + (size_t)rowsA * 2 * D;
    ushort* W1b   = Wbf;
    ushort* W2b   = Wbf + 16384;
    ushort* Winb  = Wbf + 32768;
    ushort* Woutb = Wbf + 81920;
    int* cnt_ab   = (int*)(Wbf + 98304);
    int* cnt_ba   = cnt_ab + nB;
    int* start_ab = cnt_ba + nA;
    int* start_ba = start_ab + (nB + 1);
    uintptr_t a = (uintptr_t)(start_ba + (nA + 1));
    a = (a + 15) & ~(uintptr_t)15;
    int2* ep_ab = (int2*)a;
    int2* ep_ba = ep_ab + E;

    int egrid = (E + 255) / 256;
    int n8 = (int)(nodeElems / 8);

    // features fp32 -> bf16 (single launch, both matrices)
    k_f2b2<<<(2 * n8 + 255) / 256, 256, 0, stream>>>(feat_A, feat_B, fbA, fbB, n8);

    // CSR build for both graphs (dual scan; cnt becomes the scatter cursor)
    hipMemsetAsync(cnt_ab, 0, (size_t)(nA + nB) * sizeof(int), stream);
    k_hist<<<egrid, 256, 0, stream>>>(dst_ab, dst_ba, cnt_ab, cnt_ba, E);
    k_scan2<<<2, 1024, 0, stream>>>(cnt_ab, start_ab, nB, cnt_ba, start_ba, nA);
    k_scatter<<<egrid, 256, 0, stream>>>(src_ab, dst_ab, val_ab,
                                         src_ba, dst_ba, val_ba,
                                         cnt_ab, cnt_ba, ep_ab, ep_ba, E);

    // weights -> bf16
    k_cvt<<<96, 256, 0, stream>>>(W1, W2, Win, Wout, Wbf);

    // metapath aggregations (bf16 reads, fp32 accumulate, 4x unrolled)
    k_gather_norm_bf<<<(nB + 3) / 4, 256, 0, stream>>>(fbA, ep_ab, start_ab, hB, nB);
    k_gather2_bf<<<(nA + 3) / 4, 256, 0, stream>>>(hB, fbB, ep_ba, start_ba,
                                                   hA1, hA2, nA);

    // dense epilogue: MFMA proj (both param sets, one launch), slim MFMA attention
    k_projm2<<<dim3(rowsA / 16, 2), 128, 0, stream>>>(hA1, W1b, b1, g1, be1,
                                                      hA2, W2b, b2, g2, be2, xbuf);
    k_attn2<<<rowsA / AP, 384, 0, stream>>>(xbuf, Winb, binq, Woutb, bout,
                                            lng, lnb, (float*)d_out);
}

// Round 2
// 560.667 us; speedup vs baseline: 1.0313x; 1.0313x over previous
//
#include <hip/hip_runtime.h>

// Problem constants: N_A=N_B=30000, V=2, D=128
#define D 128
#define NODE_ROW 256       // V*D elements per node
#define AP 8               // (n,v) pairs per block in k_attn2
#define AR (AP * 2)        // x-rows per block in k_attn2 (P=2)

typedef __attribute__((ext_vector_type(8))) short short8;
typedef __attribute__((ext_vector_type(4))) float floatx4;

__device__ __forceinline__ ushort f2bf(float f) {
    unsigned int u = __float_as_uint(f);
    u += 0x7fffu + ((u >> 16) & 1u);
    return (ushort)(u >> 16);
}
__device__ __forceinline__ unsigned int pk2(float a, float b) {
    return (unsigned int)f2bf(a) | ((unsigned int)f2bf(b) << 16);
}
__device__ __forceinline__ void up8(uint4 u, float* f) {
    f[0] = __uint_as_float(u.x << 16); f[1] = __uint_as_float(u.x & 0xffff0000u);
    f[2] = __uint_as_float(u.y << 16); f[3] = __uint_as_float(u.y & 0xffff0000u);
    f[4] = __uint_as_float(u.z << 16); f[5] = __uint_as_float(u.z & 0xffff0000u);
    f[6] = __uint_as_float(u.w << 16); f[7] = __uint_as_float(u.w & 0xffff0000u);
}
__device__ __forceinline__ float bf2f(ushort h) {
    return __uint_as_float(((unsigned int)h) << 16);
}
__device__ __forceinline__ short8 ldfrag(const ushort* p) {
    union { uint4 u; short8 s; } cv;
    cv.u = *(const uint4*)p;
    return cv.s;
}
__device__ __forceinline__ void acc4(float4& a, float w, uint2 u) {
    a.x += w * __uint_as_float(u.x << 16);
    a.y += w * __uint_as_float(u.x & 0xffff0000u);
    a.z += w * __uint_as_float(u.y << 16);
    a.w += w * __uint_as_float(u.y & 0xffff0000u);
}

// ---------------- fp32 -> bf16 feature convert (both matrices, one launch) ----------------
__global__ __launch_bounds__(256) void k_f2b2(
    const float* __restrict__ srcA, const float* __restrict__ srcB,
    ushort* __restrict__ dstA, ushort* __restrict__ dstB, int n8) {
    int i = blockIdx.x * 256 + threadIdx.x;
    const float* s; ushort* d; int k;
    if (i < n8) { s = srcA; d = dstA; k = i; }
    else if (i < 2 * n8) { s = srcB; d = dstB; k = i - n8; }
    else return;
    const float4* sp = (const float4*)s + (size_t)k * 2;
    float4 a = sp[0], b = sp[1];
    uint4 o;
    o.x = pk2(a.x, a.y); o.y = pk2(a.z, a.w);
    o.z = pk2(b.x, b.y); o.w = pk2(b.z, b.w);
    ((uint4*)d)[k] = o;
}

// ---------------- CSR build ----------------

__global__ __launch_bounds__(256) void k_hist(
    const int* __restrict__ dst_ab, const int* __restrict__ dst_ba,
    int* __restrict__ cnt_ab, int* __restrict__ cnt_ba, int E) {
    int i = blockIdx.x * 256 + threadIdx.x;
    if (i >= E) return;
    atomicAdd(&cnt_ab[dst_ab[i]], 1);
    atomicAdd(&cnt_ba[dst_ba[i]], 1);
}

// Both scans in one launch (block 0: ab graph, block 1: ba graph).
// Writes exclusive prefix into start[] AND back into cnt[] (scatter cursor).
__global__ __launch_bounds__(1024) void k_scan2(
    int* __restrict__ cntB, int* __restrict__ startB, int nB_,
    int* __restrict__ cntA, int* __restrict__ startA, int nA_) {
    __shared__ int part[1024];
    int* cnt; int* start; int n;
    if (blockIdx.x == 0) { cnt = cntB; start = startB; n = nB_; }
    else                 { cnt = cntA; start = startA; n = nA_; }
    int t = threadIdx.x;
    int chunk = (n + 1023) >> 10;
    int lo = min(t * chunk, n), hi = min(lo + chunk, n);
    int s = 0;
    for (int i = lo; i < hi; i++) s += cnt[i];
    part[t] = s;
    __syncthreads();
    for (int d = 1; d < 1024; d <<= 1) {
        int v = (t >= d) ? part[t - d] : 0;
        __syncthreads();
        part[t] += v;
        __syncthreads();
    }
    int off = part[t] - s;
    for (int i = lo; i < hi; i++) {
        int c = cnt[i];
        start[i] = off;
        cnt[i] = off;          // running cursor for k_scatter
        off += c;
    }
    if (t == 1023) start[n] = off;
}

// scatter with absolute cursors (cnt holds start offsets after k_scan2)
__global__ __launch_bounds__(256) void k_scatter(
    const int* __restrict__ src_ab, const int* __restrict__ dst_ab,
    const float* __restrict__ val_ab,
    const int* __restrict__ src_ba, const int* __restrict__ dst_ba,
    const float* __restrict__ val_ba,
    int* __restrict__ cur_ab, int* __restrict__ cur_ba,
    int2* __restrict__ ep_ab, int2* __restrict__ ep_ba, int E) {
    int i = blockIdx.x * 256 + threadIdx.x;
    if (i >= E) return;
    {
        int pos = atomicAdd(&cur_ab[dst_ab[i]], 1);
        ep_ab[pos] = make_int2(src_ab[i], __float_as_int(val_ab[i]));
    }
    {
        int pos = atomicAdd(&cur_ba[dst_ba[i]], 1);
        ep_ba[pos] = make_int2(src_ba[i], __float_as_int(val_ba[i]));
    }
}

// ---------------- bf16 gather SpMM (4x unrolled for MLP) ----------------

__global__ __launch_bounds__(256) void k_gather_norm_bf(
    const ushort* __restrict__ feat, const int2* __restrict__ ep,
    const int* __restrict__ start, ushort* __restrict__ out, int n) {
    int node = blockIdx.x * 4 + (threadIdx.x >> 6);
    if (node >= n) return;
    int lane = threadIdx.x & 63;
    int lo = start[node], hi = start[node + 1];
    float4 acc = make_float4(0.f, 0.f, 0.f, 0.f);
    int i = lo;
    for (; i + 3 < hi; i += 4) {
        int2 p0 = ep[i], p1 = ep[i + 1], p2 = ep[i + 2], p3 = ep[i + 3];
        uint2 u0 = ((const uint2*)(feat + (size_t)p0.x * NODE_ROW))[lane];
        uint2 u1 = ((const uint2*)(feat + (size_t)p1.x * NODE_ROW))[lane];
        uint2 u2 = ((const uint2*)(feat + (size_t)p2.x * NODE_ROW))[lane];
        uint2 u3 = ((const uint2*)(feat + (size_t)p3.x * NODE_ROW))[lane];
        acc4(acc, __int_as_float(p0.y), u0);
        acc4(acc, __int_as_float(p1.y), u1);
        acc4(acc, __int_as_float(p2.y), u2);
        acc4(acc, __int_as_float(p3.y), u3);
    }
    for (; i < hi; i++) {
        int2 p = ep[i];
        uint2 u = ((const uint2*)(feat + (size_t)p.x * NODE_ROW))[lane];
        acc4(acc, __int_as_float(p.y), u);
    }
    float ss = acc.x * acc.x + acc.y * acc.y + acc.z * acc.z + acc.w * acc.w;
    #pragma unroll
    for (int o = 16; o > 0; o >>= 1) ss += __shfl_xor(ss, o, 32);
    float sc = 1.0f / fmaxf(sqrtf(ss), 1e-12f);
    uint2 o;
    o.x = pk2(acc.x * sc, acc.y * sc);
    o.y = pk2(acc.z * sc, acc.w * sc);
    ((uint2*)(out + (size_t)node * NODE_ROW))[lane] = o;
}

__global__ __launch_bounds__(256) void k_gather2_bf(
    const ushort* __restrict__ featP, const ushort* __restrict__ featQ,
    const int2* __restrict__ ep, const int* __restrict__ start,
    ushort* __restrict__ outP, ushort* __restrict__ outQ, int n) {
    int node = blockIdx.x * 4 + (threadIdx.x >> 6);
    if (node >= n) return;
    int lane = threadIdx.x & 63;
    int lo = start[node], hi = start[node + 1];
    float4 aP = make_float4(0.f, 0.f, 0.f, 0.f);
    float4 aQ = make_float4(0.f, 0.f, 0.f, 0.f);
    int i = lo;
    for (; i + 3 < hi; i += 4) {
        int2 p0 = ep[i], p1 = ep[i + 1], p2 = ep[i + 2], p3 = ep[i + 3];
        size_t o0 = (size_t)p0.x * NODE_ROW, o1 = (size_t)p1.x * NODE_ROW;
        size_t o2 = (size_t)p2.x * NODE_ROW, o3 = (size_t)p3.x * NODE_ROW;
        uint2 uP0 = ((const uint2*)(featP + o0))[lane];
        uint2 uQ0 = ((const uint2*)(featQ + o0))[lane];
        uint2 uP1 = ((const uint2*)(featP + o1))[lane];
        uint2 uQ1 = ((const uint2*)(featQ + o1))[lane];
        uint2 uP2 = ((const uint2*)(featP + o2))[lane];
        uint2 uQ2 = ((const uint2*)(featQ + o2))[lane];
        uint2 uP3 = ((const uint2*)(featP + o3))[lane];
        uint2 uQ3 = ((const uint2*)(featQ + o3))[lane];
        float w0 = __int_as_float(p0.y), w1 = __int_as_float(p1.y);
        float w2 = __int_as_float(p2.y), w3 = __int_as_float(p3.y);
        acc4(aP, w0, uP0); acc4(aQ, w0, uQ0);
        acc4(aP, w1, uP1); acc4(aQ, w1, uQ1);
        acc4(aP, w2, uP2); acc4(aQ, w2, uQ2);
        acc4(aP, w3, uP3); acc4(aQ, w3, uQ3);
    }
    for (; i < hi; i++) {
        int2 p = ep[i];
        float w = __int_as_float(p.y);
        size_t off = (size_t)p.x * NODE_ROW;
        uint2 uP = ((const uint2*)(featP + off))[lane];
        uint2 uQ = ((const uint2*)(featQ + off))[lane];
        acc4(aP, w, uP); acc4(aQ, w, uQ);
    }
    uint2 oP, oQ;
    oP.x = pk2(aP.x, aP.y); oP.y = pk2(aP.z, aP.w);
    oQ.x = pk2(aQ.x, aQ.y); oQ.y = pk2(aQ.z, aQ.w);
    ((uint2*)(outP + (size_t)node * NODE_ROW))[lane] = oP;
    ((uint2*)(outQ + (size_t)node * NODE_ROW))[lane] = oQ;
}

// ---------------- weight fp32 -> bf16 pre-convert ----------------
__global__ __launch_bounds__(256) void k_cvt(
    const float* __restrict__ W1, const float* __restrict__ W2,
    const float* __restrict__ Win, const float* __restrict__ Wout,
    ushort* __restrict__ dst) {
    int idx = (blockIdx.x * 256 + threadIdx.x) * 4;
    if (idx >= 98304) return;
    const float* s; int off;
    if (idx < 16384)      { s = W1;  off = idx; }
    else if (idx < 32768) { s = W2;  off = idx - 16384; }
    else if (idx < 81920) { s = Win; off = idx - 32768; }
    else                  { s = Wout; off = idx - 81920; }
    float4 f = *(const float4*)(s + off);
    uint2 p;
    p.x = pk2(f.x, f.y);
    p.y = pk2(f.z, f.w);
    *(uint2*)(dst + idx) = p;
}

// ---------------- k_projm2: both projections in one launch (gridDim.y selects set) ----------------
__global__ __launch_bounds__(128) void k_projm2(
    const ushort* __restrict__ in1, const ushort* __restrict__ Wb1,
    const float* __restrict__ b1, const float* __restrict__ g1,
    const float* __restrict__ be1,
    const ushort* __restrict__ in2, const ushort* __restrict__ Wb2,
    const float* __restrict__ b2, const float* __restrict__ g2,
    const float* __restrict__ be2,
    ushort* __restrict__ xbuf) {
    __shared__ ushort xn[16][136];
    __shared__ float yb[16][128];
    int p = blockIdx.y;                       // wave-uniform select
    const ushort* in = p ? in2 : in1;
    const ushort* Wb = p ? Wb2 : Wb1;
    const float*  b  = p ? b2  : b1;
    const float*  g  = p ? g2  : g1;
    const float*  be = p ? be2 : be1;
    int t = threadIdx.x;
    size_t rowbase = (size_t)blockIdx.x * 16;
    int r = t >> 3, i = t & 7;

    {
        const ushort* gp = in + (rowbase + r) * D + i * 16;
        float v[16];
        up8(((const uint4*)gp)[0], v);
        up8(((const uint4*)gp)[1], v + 8);
        float ss = 0.f;
        #pragma unroll
        for (int e = 0; e < 16; e++) ss += v[e] * v[e];
        ss += __shfl_xor(ss, 1, 8);
        ss += __shfl_xor(ss, 2, 8);
        ss += __shfl_xor(ss, 4, 8);
        float sc = 1.0f / fmaxf(sqrtf(ss), 1e-12f);
        uint4 w0, w1;
        w0.x = pk2(v[0]*sc, v[1]*sc);   w0.y = pk2(v[2]*sc, v[3]*sc);
        w0.z = pk2(v[4]*sc, v[5]*sc);   w0.w = pk2(v[6]*sc, v[7]*sc);
        w1.x = pk2(v[8]*sc, v[9]*sc);   w1.y = pk2(v[10]*sc, v[11]*sc);
        w1.z = pk2(v[12]*sc, v[13]*sc); w1.w = pk2(v[14]*sc, v[15]*sc);
        ushort* dst = &xn[r][i * 16];
        ((uint4*)dst)[0] = w0;
        ((uint4*)dst)[1] = w1;
    }
    __syncthreads();

    {
        int lane = t & 63, w = t >> 6, c = lane & 15, quad = lane >> 4;
        short8 af[4];
        #pragma unroll
        for (int kt = 0; kt < 4; kt++)
            af[kt] = ldfrag(&xn[c][kt * 32 + quad * 8]);
        #pragma unroll
        for (int nt2 = 0; nt2 < 4; nt2++) {
            int j = (w * 4 + nt2) * 16 + c;
            floatx4 acc = {0.f, 0.f, 0.f, 0.f};
            #pragma unroll
            for (int kt = 0; kt < 4; kt++) {
                short8 bfr = ldfrag(Wb + (size_t)j * 128 + kt * 32 + quad * 8);
                acc = __builtin_amdgcn_mfma_f32_16x16x32_bf16(af[kt], bfr, acc, 0, 0, 0);
            }
            float bj = b[j];
            #pragma unroll
            for (int rg = 0; rg < 4; rg++)
                yb[quad * 4 + rg][j] = acc[rg] + bj;
        }
    }
    __syncthreads();

    {
        float v[16];
        const float* yr = &yb[r][i * 16];
        #pragma unroll
        for (int e = 0; e < 16; e++) v[e] = yr[e];
        float s1 = 0.f, s2 = 0.f;
        #pragma unroll
        for (int e = 0; e < 16; e++) { s1 += v[e]; s2 += v[e] * v[e]; }
        s1 += __shfl_xor(s1, 1, 8); s2 += __shfl_xor(s2, 1, 8);
        s1 += __shfl_xor(s1, 2, 8); s2 += __shfl_xor(s2, 2, 8);
        s1 += __shfl_xor(s1, 4, 8); s2 += __shfl_xor(s2, 4, 8);
        float mu = s1 * (1.0f / 128.0f);
        float var = s2 * (1.0f / 128.0f) - mu * mu;
        float rs = rsqrtf(var + 1e-5f);
        const float* gg = g + i * 16;
        const float* bb = be + i * 16;
        float res[16];
        #pragma unroll
        for (int e = 0; e < 16; e++)
            res[e] = fmaxf((v[e] - mu) * rs * gg[e] + bb[e], 0.f);
        ushort* op = xbuf + ((rowbase + r) * 2 + p) * D + i * 16;
        uint4 w0, w1;
        w0.x = pk2(res[0], res[1]);   w0.y = pk2(res[2], res[3]);
        w0.z = pk2(res[4], res[5]);   w0.w = pk2(res[6], res[7]);
        w1.x = pk2(res[8], res[9]);   w1.y = pk2(res[10], res[11]);
        w1.z = pk2(res[12], res[13]); w1.w = pk2(res[14], res[15]);
        ((uint4*)op)[0] = w0;
        ((uint4*)op)[1] = w1;
    }
}

// ---------------- k_attn2: 256 threads, all phases fully occupied ----------------
// qk padded to 260 floats/row (stride 1040B): row-starts spread across banks
// (4*r mod 32) -> QKV writes 2-way (free), LN-stats reads 16-way -> 2-way.
// launch_bounds(256,5): 5 blocks/CU (LDS-capped anyway) but VGPR budget ~96
// so the compiler can pipeline Winb/Woutb fragment loads against MFMA.
#define QKS 260
__global__ __launch_bounds__(256, 5) void k_attn2(
    const ushort* __restrict__ xbuf,
    const ushort* __restrict__ Winb, const float* __restrict__ binq,
    const ushort* __restrict__ Woutb, const float* __restrict__ bout,
    const float* __restrict__ lng, const float* __restrict__ lnb,
    float* __restrict__ out) {
    __shared__ ushort xb[AR][136];     // x rows bf16 (A-operand + residual)
    __shared__ float qk[AR][QKS];      // q(scaled),k fp32; y reuses 0..127
    __shared__ ushort vb[AR][136];     // v bf16
    __shared__ ushort ob[AR][136];     // attn-out bf16 (A-operand)
    __shared__ float mu_s[AR], rs_s[AR];
    int t = threadIdx.x;
    int lane = t & 63, w = t >> 6;
    int c = lane & 15, quad = lane >> 4;
    size_t pairbase = (size_t)blockIdx.x * AP;
    size_t rowbase = pairbase * 2;

    // load bf16 x into xb (512 uint2 loads, 2 per thread)
    const uint2* gx = (const uint2*)(xbuf + rowbase * D);
    #pragma unroll
    for (int i = t; i < AR * D / 4; i += 256) {
        int r = i >> 5;
        int col = (i & 31) * 4;
        *(uint2*)&xb[r][col] = gx[i];
    }
    __syncthreads();

    // QKV GEMM via MFMA: M=16, N=384 (wave w -> ntiles w*6..w*6+5)
    {
        short8 af[4];
        #pragma unroll
        for (int kt = 0; kt < 4; kt++)
            af[kt] = ldfrag(&xb[c][kt * 32 + quad * 8]);
        #pragma unroll
        for (int nt2 = 0; nt2 < 6; nt2++) {
            int j = (w * 6 + nt2) * 16 + c;
            floatx4 acc = {0.f, 0.f, 0.f, 0.f};
            #pragma unroll
            for (int kt = 0; kt < 4; kt++) {
                short8 bfr = ldfrag(Winb + (size_t)j * 128 + kt * 32 + quad * 8);
                acc = __builtin_amdgcn_mfma_f32_16x16x32_bf16(af[kt], bfr, acc, 0, 0, 0);
            }
            float bj = binq[j];
            if (j < 256) {
                float sc = (j < 128) ? 0.17677669529663687f : 1.0f;
                #pragma unroll
                for (int rg = 0; rg < 4; rg++)
                    qk[quad * 4 + rg][j] = (acc[rg] + bj) * sc;
            } else {
                #pragma unroll
                for (int rg = 0; rg < 4; rg++)
                    vb[quad * 4 + rg][j - 256] = f2bf(acc[rg] + bj);
            }
        }
    }
    __syncthreads();

    // FUSED scores + softmax + a@v: all 256 threads, attention weights in regs.
    // t = [pp:3][h:2][pq:1][kk:1][half:1]; each thread: 16-elem partial dot,
    // shfl(1) completes dot, shfl(2) exchanges the two scores, then writes its
    // 8 output columns of ob.
    {
        int half = t & 1, kk = (t >> 1) & 1, pq = (t >> 2) & 1;
        int h = (t >> 3) & 3, pp = t >> 5;
        int qrow = 2 * pp + pq;
        const float4* qp = (const float4*)&qk[qrow][h * 32 + half * 16];
        const float4* kp = (const float4*)&qk[2 * pp + kk][128 + h * 32 + half * 16];
        float s = 0.f;
        #pragma unroll
        for (int m = 0; m < 4; m++) {
            float4 qv = qp[m], kv = kp[m];
            s += qv.x * kv.x + qv.y * kv.y + qv.z * kv.z + qv.w * kv.w;
        }
        s += __shfl_xor(s, 1, 64);          // complete 32-elem dot
        float so = __shfl_xor(s, 2, 64);    // partner score (other kk)
        float s0 = kk ? so : s;
        float s1 = kk ? s : so;
        float m0 = fmaxf(s0, s1);
        float e0 = __expf(s0 - m0), e1 = __expf(s1 - m0);
        float inv = 1.f / (e0 + e1);
        float a0 = e0 * inv, a1 = e1 * inv;
        int cbase = h * 32 + kk * 16 + half * 8;
        const uint2* v0p = (const uint2*)&vb[2 * pp][cbase];
        const uint2* v1p = (const uint2*)&vb[2 * pp + 1][cbase];
        ushort* op = &ob[qrow][cbase];
        #pragma unroll
        for (int m = 0; m < 2; m++) {
            uint2 u0 = v0p[m], u1 = v1p[m];
            float o0 = a0 * __uint_as_float(u0.x << 16)         + a1 * __uint_as_float(u1.x << 16);
            float o1 = a0 * __uint_as_float(u0.x & 0xffff0000u) + a1 * __uint_as_float(u1.x & 0xffff0000u);
            float o2 = a0 * __uint_as_float(u0.y << 16)         + a1 * __uint_as_float(u1.y << 16);
            float o3 = a0 * __uint_as_float(u0.y & 0xffff0000u) + a1 * __uint_as_float(u1.y & 0xffff0000u);
            uint2 pw;
            pw.x = pk2(o0, o1); pw.y = pk2(o2, o3);
            ((uint2*)op)[m] = pw;
        }
    }
    __syncthreads();

    // out-proj via MFMA + bias + residual -> y in qk cols 0..127 (q,k dead)
    {
        short8 af[4];
        #pragma unroll
        for (int kt = 0; kt < 4; kt++)
            af[kt] = ldfrag(&ob[c][kt * 32 + quad * 8]);
        #pragma unroll
        for (int nt2 = 0; nt2 < 2; nt2++) {
            int j = (w * 2 + nt2) * 16 + c;
            floatx4 acc = {0.f, 0.f, 0.f, 0.f};
            #pragma unroll
            for (int kt = 0; kt < 4; kt++) {
                short8 bfr = ldfrag(Woutb + (size_t)j * 128 + kt * 32 + quad * 8);
                acc = __builtin_amdgcn_mfma_f32_16x16x32_bf16(af[kt], bfr, acc, 0, 0, 0);
            }
            float bj = bout[j];
            #pragma unroll
            for (int rg = 0; rg < 4; rg++) {
                int row = quad * 4 + rg;
                qk[row][j] = acc[rg] + bj + bf2f(xb[row][j]);
            }
        }
    }
    __syncthreads();

    // LN stats per row on y (qk cols 0..127)
    if (t < 128) {
        int r = t >> 3, i = t & 7;
        float s1 = 0.f, s2 = 0.f;
        const float* yr = &qk[r][i * 16];
        #pragma unroll
        for (int cc = 0; cc < 16; cc++) { float v = yr[cc]; s1 += v; s2 += v * v; }
        s1 += __shfl_down(s1, 4, 8); s2 += __shfl_down(s2, 4, 8);
        s1 += __shfl_down(s1, 2, 8); s2 += __shfl_down(s2, 2, 8);
        s1 += __shfl_down(s1, 1, 8); s2 += __shfl_down(s2, 1, 8);
        if (i == 0) {
            float mu = s1 / D;
            float var = s2 / D - mu * mu;
            mu_s[r] = mu; rs_s[r] = rsqrtf(var + 1e-5f);
        }
    }
    __syncthreads();

    // LN apply + mean over P
    if (t < 128) {
        int j = t;
        float gj = lng[j], bj = lnb[j];
        #pragma unroll
        for (int pp = 0; pp < AP; pp++) {
            int r0 = pp * 2, r1 = r0 + 1;
            float v0 = (qk[r0][j] - mu_s[r0]) * rs_s[r0] * gj + bj;
            float v1 = (qk[r1][j] - mu_s[r1]) * rs_s[r1] * gj + bj;
            out[(pairbase + pp) * D + j] = 0.5f * (v0 + v1);
        }
    }
}

extern "C" void kernel_launch(void* const* d_in, const int* in_sizes, int n_in,
                              void* d_out, int out_size, void* d_ws, size_t ws_size,
                              hipStream_t stream) {
    const float* feat_A = (const float*)d_in[0];
    const float* feat_B = (const float*)d_in[1];
    const int*   src_ab = (const int*)d_in[2];
    const int*   dst_ab = (const int*)d_in[3];
    const float* val_ab = (const float*)d_in[4];
    const int*   src_ba = (const int*)d_in[5];
    const int*   dst_ba = (const int*)d_in[6];
    const float* val_ba = (const float*)d_in[7];
    const float* W1 = (const float*)d_in[8];
    const float* b1 = (const float*)d_in[9];
    const float* g1 = (const float*)d_in[10];
    const float* be1 = (const float*)d_in[11];
    const float* W2 = (const float*)d_in[12];
    const float* b2 = (const float*)d_in[13];
    const float* g2 = (const float*)d_in[14];
    const float* be2 = (const float*)d_in[15];
    const float* Win = (const float*)d_in[16];
    const float* binq = (const float*)d_in[17];
    const float* Wout = (const float*)d_in[18];
    const float* bout = (const float*)d_in[19];
    const float* lng = (const float*)d_in[20];
    const float* lnb = (const float*)d_in[21];

    int E  = in_sizes[2];
    int nA = in_sizes[0] / NODE_ROW;   // 30000
    int nB = in_sizes[1] / NODE_ROW;   // 30000
    int rowsA = nA * 2;                // N_A * V = 60000
    size_t nodeElems = (size_t)nA * NODE_ROW;

    // Workspace layout (identical to passing R6)
    ushort* fbA  = (ushort*)d_ws;
    ushort* fbB  = fbA + nodeElems;
    ushort* hB   = fbB + nodeElems;
    ushort* hA1  = hB + nodeElems;
    ushort* hA2  = hA1 + nodeElems;
    ushort* xbuf = hA2 + nodeElems;
    ushort* Wbf  = xbuf + (size_t)rowsA * 2 * D;
    ushort* W1b   = Wbf;
    ushort* W2b   = Wbf + 16384;
    ushort* Winb  = Wbf + 32768;
    ushort* Woutb = Wbf + 81920;
    int* cnt_ab   = (int*)(Wbf + 98304);
    int* cnt_ba   = cnt_ab + nB;
    int* start_ab = cnt_ba + nA;
    int* start_ba = start_ab + (nB + 1);
    uintptr_t a = (uintptr_t)(start_ba + (nA + 1));
    a = (a + 15) & ~(uintptr_t)15;
    int2* ep_ab = (int2*)a;
    int2* ep_ba = ep_ab + E;

    int egrid = (E + 255) / 256;
    int n8 = (int)(nodeElems / 8);

    // features fp32 -> bf16 (single launch, both matrices)
    k_f2b2<<<(2 * n8 + 255) / 256, 256, 0, stream>>>(feat_A, feat_B, fbA, fbB, n8);

    // CSR build for both graphs (dual scan; cnt becomes the scatter cursor)
    hipMemsetAsync(cnt_ab, 0, (size_t)(nA + nB) * sizeof(int), stream);
    k_hist<<<egrid, 256, 0, stream>>>(dst_ab, dst_ba, cnt_ab, cnt_ba, E);
    k_scan2<<<2, 1024, 0, stream>>>(cnt_ab, start_ab, nB, cnt_ba, start_ba, nA);
    k_scatter<<<egrid, 256, 0, stream>>>(src_ab, dst_ab, val_ab,
                                         src_ba, dst_ba, val_ba,
                                         cnt_ab, cnt_ba, ep_ab, ep_ba, E);

    // weights -> bf16
    k_cvt<<<96, 256, 0, stream>>>(W1, W2, Win, Wout, Wbf);

    // metapath aggregations (bf16 reads, fp32 accumulate, 4x unrolled)
    k_gather_norm_bf<<<(nB + 3) / 4, 256, 0, stream>>>(fbA, ep_ab, start_ab, hB, nB);
    k_gather2_bf<<<(nA + 3) / 4, 256, 0, stream>>>(hB, fbB, ep_ba, start_ba,
                                                   hA1, hA2, nA);

    // dense epilogue: MFMA proj (both param sets, one launch), slim MFMA attention
    k_projm2<<<dim3(rowsA / 16, 2), 128, 0, stream>>>(hA1, W1b, b1, g1, be1,
                                                      hA2, W2b, b2, g2, be2, xbuf);
    k_attn2<<<rowsA / AP, 256, 0, stream>>>(xbuf, Winb, binq, Woutb, bout,
                                            lng, lnb, (float*)d_out);
}